// Round 2
// baseline (443.068 us; speedup 1.0000x reference)
//
#include <hip/hip_runtime.h>

// FWHT over groups of 128 consecutive fp32 elements, scale 1/sqrt(128).
// Thread owns 16 consecutive elements (4x float4): FWHT bits 0-3 in-register,
// bits 4-6 via __shfl_xor masks 1,2,4 (8 lanes per group, never crosses the
// wave). 3 DS-ops/element vs 5 in the 4-elem version; 4 outstanding vmem
// loads per thread for latency hiding.

__global__ __launch_bounds__(256) void fwht128_kernel(const float* __restrict__ x,
                                                      float* __restrict__ out,
                                                      int nthreads) {
    int idx = blockIdx.x * blockDim.x + threadIdx.x;
    if (idx >= nthreads) return;

    const float4* __restrict__ in4 = (const float4*)x;
    float4* __restrict__ out4 = (float4*)out;

    // Load 16 consecutive floats as 4 float4s (issued back-to-back).
    float4 v0 = in4[4 * idx + 0];
    float4 v1 = in4[4 * idx + 1];
    float4 v2 = in4[4 * idx + 2];
    float4 v3 = in4[4 * idx + 3];

    float r[16] = {v0.x, v0.y, v0.z, v0.w,
                   v1.x, v1.y, v1.z, v1.w,
                   v2.x, v2.y, v2.z, v2.w,
                   v3.x, v3.y, v3.z, v3.w};

    // In-register butterflies: element-index bits 0..3 (h = 1,2,4,8).
    #pragma unroll
    for (int h = 1; h <= 8; h <<= 1) {
        #pragma unroll
        for (int j = 0; j < 16; ++j) {
            if (!(j & h)) {
                float a = r[j];
                float b = r[j ^ h];
                r[j]     = a + b;
                r[j ^ h] = a - b;
            }
        }
    }

    // Cross-lane butterflies: element bits 4,5,6 <-> lane bits 0,1,2.
    const int lane = threadIdx.x & 63;
    #pragma unroll
    for (int m = 1; m <= 4; m <<= 1) {
        const bool upper = (lane & m) != 0;
        #pragma unroll
        for (int j = 0; j < 16; ++j) {
            float p = __shfl_xor(r[j], m, 64);
            // lower half: mine + partner; upper half: partner - mine
            r[j] = upper ? (p - r[j]) : (r[j] + p);
        }
    }

    constexpr float SCALE = 0.08838834764831845f; // 1/sqrt(128)
    float4 o0 = {r[0] * SCALE,  r[1] * SCALE,  r[2] * SCALE,  r[3] * SCALE};
    float4 o1 = {r[4] * SCALE,  r[5] * SCALE,  r[6] * SCALE,  r[7] * SCALE};
    float4 o2 = {r[8] * SCALE,  r[9] * SCALE,  r[10] * SCALE, r[11] * SCALE};
    float4 o3 = {r[12] * SCALE, r[13] * SCALE, r[14] * SCALE, r[15] * SCALE};
    out4[4 * idx + 0] = o0;
    out4[4 * idx + 1] = o1;
    out4[4 * idx + 2] = o2;
    out4[4 * idx + 3] = o3;
}

extern "C" void kernel_launch(void* const* d_in, const int* in_sizes, int n_in,
                              void* d_out, int out_size, void* d_ws, size_t ws_size,
                              hipStream_t stream) {
    const float* x = (const float*)d_in[0];
    float* out = (float*)d_out;
    int n = in_sizes[0];           // 4*4096*4096 = 67,108,864 (divisible by 128)
    int nthreads = n >> 4;         // 16 elements per thread
    const int block = 256;
    int grid = (nthreads + block - 1) / block;
    fwht128_kernel<<<grid, block, 0, stream>>>(x, out, nthreads);
}